// Round 1
// baseline (77.118 us; speedup 1.0000x reference)
//
#include <hip/hip_runtime.h>

#define COLS 4096
#define TROWS 4096
#define PAIRS (TROWS - 1)   // 4095

// Phase 1: each thread scans one column over one chunk of pairs.
// Emits per (chunk, column) record of 8 floats:
//   [0]=head_sum [1]=head_cnt [2]=tail_sum [3]=tail_cnt
//   [4]=interior_mean_sum [5]=interior_run_cnt [6]=all_ones_flag [7]=pad
__global__ void msi_phase1(const float* __restrict__ p, const int* __restrict__ s,
                           float* __restrict__ recs, int NC, int PCH) {
    int r = blockIdx.x * blockDim.x + threadIdx.x;   // column
    int c = blockIdx.y;                              // chunk index
    int t0 = c * PCH;
    int t1 = t0 + PCH;
    if (t1 > PAIRS) t1 = PAIRS;

    const float* pc = p + r;
    const int*   sc = s + r;

    float p_prev = pc[(size_t)t0 * COLS];
    int   s_prev = sc[(size_t)t0 * COLS];

    float cur_sum = 0.f; int cur_cnt = 0;
    float h_sum = 0.f;   int h_cnt = 0;
    bool  head_done = false;
    float msum = 0.f;    int mcnt = 0;

    #pragma unroll 4
    for (int t = t0; t < t1; ++t) {
        float p_cur = pc[(size_t)(t + 1) * COLS];
        int   s_cur = sc[(size_t)(t + 1) * COLS];
        float d = p_cur - p_prev;
        if (s_cur == s_prev) {
            cur_sum += d * d;
            cur_cnt += 1;
        } else {
            if (!head_done) {
                h_sum = cur_sum; h_cnt = cur_cnt; head_done = true;
            } else if (cur_cnt > 0) {
                msum += cur_sum / (float)cur_cnt; mcnt += 1;
            }
            cur_sum = 0.f; cur_cnt = 0;
        }
        p_prev = p_cur; s_prev = s_cur;
    }

    float4 a, b;
    if (!head_done) {
        // whole chunk is a single (possibly empty) open run
        a = make_float4(cur_sum, (float)cur_cnt, cur_sum, (float)cur_cnt);
        b = make_float4(msum, (float)mcnt, 1.0f, 0.f);
    } else {
        a = make_float4(h_sum, (float)h_cnt, cur_sum, (float)cur_cnt);
        b = make_float4(msum, (float)mcnt, 0.0f, 0.f);
    }
    float4* out = (float4*)recs + (size_t)(c * COLS + r) * 2;
    out[0] = a;
    out[1] = b;
}

// Phase 2: one thread per column walks NC chunk records, merging run carries
// exactly across chunk boundaries. Block-reduces (mean_sum, run_cnt) in double.
__global__ void msi_phase2(const float* __restrict__ recs, double* __restrict__ partials,
                           int NC) {
    int r = blockIdx.x * blockDim.x + threadIdx.x;
    double msum = 0.0, mcnt = 0.0;
    float c_sum = 0.f, c_cnt = 0.f;   // open-run carry

    for (int c = 0; c < NC; ++c) {
        const float4* rp = (const float4*)recs + (size_t)(c * COLS + r) * 2;
        float4 a = rp[0];
        float4 b = rp[1];
        if (b.z != 0.f) {
            // chunk is entirely one run: extend carry, stays open
            c_sum += a.x; c_cnt += a.y;
        } else {
            // close carry + head run
            float mk_s = c_sum + a.x;
            float mk_c = c_cnt + a.y;
            if (mk_c > 0.f) { msum += (double)(mk_s / mk_c); mcnt += 1.0; }
            // interior complete runs
            msum += (double)b.x; mcnt += (double)b.y;
            // new carry = tail run
            c_sum = a.z; c_cnt = a.w;
        }
    }
    if (c_cnt > 0.f) { msum += (double)(c_sum / c_cnt); mcnt += 1.0; }

    __shared__ double ls[256];
    __shared__ double lc[256];
    int tid = threadIdx.x;
    ls[tid] = msum; lc[tid] = mcnt;
    __syncthreads();
    for (int off = 128; off > 0; off >>= 1) {
        if (tid < off) { ls[tid] += ls[tid + off]; lc[tid] += lc[tid + off]; }
        __syncthreads();
    }
    if (tid == 0) {
        partials[blockIdx.x * 2 + 0] = ls[0];
        partials[blockIdx.x * 2 + 1] = lc[0];
    }
}

// Phase 3: reduce block partials, write final scalar.
__global__ void msi_phase3(const double* __restrict__ partials, int nparts,
                           float* __restrict__ out) {
    int tid = threadIdx.x;
    double msum = 0.0, mcnt = 0.0;
    if (tid < nparts) {
        msum = partials[tid * 2 + 0];
        mcnt = partials[tid * 2 + 1];
    }
    for (int off = 32; off > 0; off >>= 1) {
        msum += __shfl_down(msum, off);
        mcnt += __shfl_down(mcnt, off);
    }
    if (tid == 0) out[0] = (mcnt > 0.0) ? (float)(msum / mcnt) : 0.f;
}

extern "C" void kernel_launch(void* const* d_in, const int* in_sizes, int n_in,
                              void* d_out, int out_size, void* d_ws, size_t ws_size,
                              hipStream_t stream) {
    const float* p = (const float*)d_in[0];
    const int*   s = (const int*)d_in[1];
    float* out = (float*)d_out;

    // choose number of chunks that fits in workspace
    int NC = 32;
    const int nblocks2 = COLS / 256;  // 16
    auto need = [&](int nc) -> size_t {
        return (size_t)nc * COLS * 32 + (size_t)nblocks2 * 2 * sizeof(double);
    };
    while (NC > 1 && need(NC) > ws_size) NC >>= 1;
    int PCH = (PAIRS + NC - 1) / NC;

    float*  recs     = (float*)d_ws;
    double* partials = (double*)((char*)d_ws + (size_t)NC * COLS * 32);

    dim3 g1(COLS / 256, NC);
    msi_phase1<<<g1, 256, 0, stream>>>(p, s, recs, NC, PCH);
    msi_phase2<<<nblocks2, 256, 0, stream>>>(recs, partials, NC);
    msi_phase3<<<1, 64, 0, stream>>>(partials, nblocks2, out);
}

// Round 2
// 69.556 us; speedup vs baseline: 1.1087x; 1.1087x over previous
//
#include <hip/hip_runtime.h>

#define COLS 4096
#define C4   (COLS / 4)
#define TROWS 4096
#define PAIRS (TROWS - 1)   // 4095

// ---------------------------------------------------------------------------
// Phase 1: each thread scans FOUR adjacent columns (float4/int4 loads) over one
// chunk of pairs. Fully predicated run tracking so loads pipeline.
// Record per (chunk, column), 8 floats:
//   [0]=head_sum [1]=head_cnt [2]=tail_sum [3]=tail_cnt
//   [4]=interior_mean_sum [5]=interior_run_cnt [6]=all_ones_flag [7]=pad
// ---------------------------------------------------------------------------
__global__ void msi_phase1(const float4* __restrict__ p4, const int4* __restrict__ s4,
                           float* __restrict__ recs, int NC, int PCH) {
    int g = blockIdx.x * blockDim.x + threadIdx.x;   // column group (4 cols)
    int c = blockIdx.y;                              // chunk index
    int t0 = c * PCH;
    int t1 = t0 + PCH;
    if (t1 > PAIRS) t1 = PAIRS;

    float4 pp = p4[(size_t)t0 * C4 + g];
    int4   sp = s4[(size_t)t0 * C4 + g];
    float pprev[4] = {pp.x, pp.y, pp.z, pp.w};
    int   sprev[4] = {sp.x, sp.y, sp.z, sp.w};

    float cs[4] = {0.f, 0.f, 0.f, 0.f};   // current run sum
    int   cc[4] = {0, 0, 0, 0};           // current run count
    float hs[4] = {0.f, 0.f, 0.f, 0.f};   // head run sum
    int   hc[4] = {0, 0, 0, 0};           // head run count
    int   hd[4] = {0, 0, 0, 0};           // head_done
    float ms[4] = {0.f, 0.f, 0.f, 0.f};   // interior mean sum
    int   mc[4] = {0, 0, 0, 0};           // interior run count

#define PROC(PV, SV)                                                          \
    {                                                                         \
        float pcur[4] = {(PV).x, (PV).y, (PV).z, (PV).w};                     \
        int   scur[4] = {(SV).x, (SV).y, (SV).z, (SV).w};                     \
        _Pragma("unroll")                                                     \
        for (int k = 0; k < 4; ++k) {                                         \
            float d = pcur[k] - pprev[k];                                     \
            bool same = (scur[k] == sprev[k]);                                \
            bool first = !same && !hd[k];                                     \
            bool interior = !same && hd[k] && (cc[k] > 0);                    \
            hs[k] = first ? cs[k] : hs[k];                                    \
            hc[k] = first ? cc[k] : hc[k];                                    \
            float mean = cs[k] * __builtin_amdgcn_rcpf((float)cc[k]);         \
            ms[k] += interior ? mean : 0.f;                                   \
            mc[k] += interior ? 1 : 0;                                        \
            hd[k] = hd[k] | (same ? 0 : 1);                                   \
            cs[k] = same ? cs[k] + d * d : 0.f;                               \
            cc[k] = same ? cc[k] + 1 : 0;                                     \
            pprev[k] = pcur[k];                                               \
            sprev[k] = scur[k];                                               \
        }                                                                     \
    }

    int t = t0;
    int nb = (t1 - t0) >> 2;
    for (int b = 0; b < nb; ++b) {
        size_t base = (size_t)(t + 1) * C4 + g;
        float4 P0 = p4[base];
        float4 P1 = p4[base + C4];
        float4 P2 = p4[base + 2 * C4];
        float4 P3 = p4[base + 3 * C4];
        int4   S0 = s4[base];
        int4   S1 = s4[base + C4];
        int4   S2 = s4[base + 2 * C4];
        int4   S3 = s4[base + 3 * C4];
        PROC(P0, S0);
        PROC(P1, S1);
        PROC(P2, S2);
        PROC(P3, S3);
        t += 4;
    }
    for (; t < t1; ++t) {
        size_t base = (size_t)(t + 1) * C4 + g;
        float4 P0 = p4[base];
        int4   S0 = s4[base];
        PROC(P0, S0);
    }
#undef PROC

    // Emit 4 records (consecutive columns -> 128 B contiguous store region)
    #pragma unroll
    for (int k = 0; k < 4; ++k) {
        int r = 4 * g + k;
        float4 a, b;
        if (!hd[k]) {
            a = make_float4(cs[k], (float)cc[k], cs[k], (float)cc[k]);
            b = make_float4(ms[k], (float)mc[k], 1.0f, 0.f);
        } else {
            a = make_float4(hs[k], (float)hc[k], cs[k], (float)cc[k]);
            b = make_float4(ms[k], (float)mc[k], 0.0f, 0.f);
        }
        float4* out = (float4*)recs + (size_t)(c * COLS + r) * 2;
        out[0] = a;
        out[1] = b;
    }
}

// ---------------------------------------------------------------------------
// Phase 2: one thread per column merges NC chunk records (exact run stitching
// across chunk boundaries). Predicated body so loads prefetch under unroll.
// ---------------------------------------------------------------------------
__global__ void msi_phase2(const float* __restrict__ recs, double* __restrict__ partials,
                           int NC) {
    int r = blockIdx.x * blockDim.x + threadIdx.x;
    double msum = 0.0, mcnt = 0.0;
    float c_sum = 0.f, c_cnt = 0.f;   // open-run carry

    #pragma unroll 4
    for (int c = 0; c < NC; ++c) {
        const float4* rp = (const float4*)recs + (size_t)(c * COLS + r) * 2;
        float4 a = rp[0];
        float4 b = rp[1];
        bool allone = (b.z != 0.f);
        float mk_s = c_sum + a.x;
        float mk_c = c_cnt + a.y;
        bool closev = !allone && (mk_c > 0.f);
        msum += closev ? (double)(mk_s / mk_c) : 0.0;
        mcnt += closev ? 1.0 : 0.0;
        msum += allone ? 0.0 : (double)b.x;
        mcnt += allone ? 0.0 : (double)b.y;
        c_sum = allone ? c_sum + a.x : a.z;
        c_cnt = allone ? c_cnt + a.y : a.w;
    }
    if (c_cnt > 0.f) { msum += (double)(c_sum / c_cnt); mcnt += 1.0; }

    __shared__ double ls[256];
    __shared__ double lc[256];
    int tid = threadIdx.x;
    ls[tid] = msum; lc[tid] = mcnt;
    __syncthreads();
    for (int off = 128; off > 0; off >>= 1) {
        if (tid < off) { ls[tid] += ls[tid + off]; lc[tid] += lc[tid + off]; }
        __syncthreads();
    }
    if (tid == 0) {
        partials[blockIdx.x * 2 + 0] = ls[0];
        partials[blockIdx.x * 2 + 1] = lc[0];
    }
}

// Phase 3: reduce block partials, write final scalar.
__global__ void msi_phase3(const double* __restrict__ partials, int nparts,
                           float* __restrict__ out) {
    int tid = threadIdx.x;
    double msum = 0.0, mcnt = 0.0;
    if (tid < nparts) {
        msum = partials[tid * 2 + 0];
        mcnt = partials[tid * 2 + 1];
    }
    for (int off = 32; off > 0; off >>= 1) {
        msum += __shfl_down(msum, off);
        mcnt += __shfl_down(mcnt, off);
    }
    if (tid == 0) out[0] = (mcnt > 0.0) ? (float)(msum / mcnt) : 0.f;
}

extern "C" void kernel_launch(void* const* d_in, const int* in_sizes, int n_in,
                              void* d_out, int out_size, void* d_ws, size_t ws_size,
                              hipStream_t stream) {
    const float4* p = (const float4*)d_in[0];
    const int4*   s = (const int4*)d_in[1];
    float* out = (float*)d_out;

    int NC = 64;
    const int nblocks2 = COLS / 256;  // 16
    auto need = [&](int nc) -> size_t {
        return (size_t)nc * COLS * 32 + (size_t)nblocks2 * 2 * sizeof(double);
    };
    while (NC > 1 && need(NC) > ws_size) NC >>= 1;
    int PCH = (PAIRS + NC - 1) / NC;

    float*  recs     = (float*)d_ws;
    double* partials = (double*)((char*)d_ws + (size_t)NC * COLS * 32);

    dim3 g1(C4 / 256, NC);   // 4 x NC blocks of 256 threads
    msi_phase1<<<g1, 256, 0, stream>>>(p, s, recs, NC, PCH);
    msi_phase2<<<nblocks2, 256, 0, stream>>>(recs, partials, NC);
    msi_phase3<<<1, 64, 0, stream>>>(partials, nblocks2, out);
}

// Round 3
// 52.770 us; speedup vs baseline: 1.4614x; 1.3181x over previous
//
#include <hip/hip_runtime.h>

#define COLS 4096
#define C4   (COLS / 4)
#define TROWS 4096
#define PAIRS (TROWS - 1)   // 4095

// ---------------------------------------------------------------------------
// Mergeable run record: head run (closed at first diff unless ao), tail run
// (open), interior sum-of-means/count, all-one flag (whole span one open run).
// ---------------------------------------------------------------------------
struct Rec { float hs, hc, ts, tc, ms, mc, ao; };

__device__ inline Rec rec_merge(const Rec& L, const Rec& R) {
    Rec o;
    if (L.ao != 0.f && R.ao != 0.f) {
        o.hs = L.hs + R.hs; o.hc = L.hc + R.hc;
        o.ts = o.hs;        o.tc = o.hc;
        o.ms = 0.f; o.mc = 0.f; o.ao = 1.f;
    } else if (L.ao != 0.f) {
        o.hs = L.hs + R.hs; o.hc = L.hc + R.hc;   // L's run extends R's head
        o.ts = R.ts; o.tc = R.tc;
        o.ms = R.ms; o.mc = R.mc; o.ao = 0.f;
    } else if (R.ao != 0.f) {
        o.hs = L.hs; o.hc = L.hc;
        o.ts = L.ts + R.hs; o.tc = L.tc + R.hc;   // L's tail extends through R
        o.ms = L.ms; o.mc = L.mc; o.ao = 0.f;
    } else {
        o.hs = L.hs; o.hc = L.hc;
        o.ts = R.ts; o.tc = R.tc;
        float js = L.ts + R.hs, jc = L.tc + R.hc; // join run closes
        bool v = jc > 0.f;
        o.ms = L.ms + R.ms + (v ? js / jc : 0.f);
        o.mc = L.mc + R.mc + (v ? 1.f : 0.f);
        o.ao = 0.f;
    }
    return o;
}

__device__ inline Rec rec_load(const float4* base, size_t idx) {
    float4 a = base[idx * 2], b = base[idx * 2 + 1];
    Rec r; r.hs = a.x; r.hc = a.y; r.ts = a.z; r.tc = a.w;
    r.ms = b.x; r.mc = b.y; r.ao = b.z; return r;
}
__device__ inline void rec_store(float4* base, size_t idx, const Rec& r) {
    base[idx * 2]     = make_float4(r.hs, r.hc, r.ts, r.tc);
    base[idx * 2 + 1] = make_float4(r.ms, r.mc, r.ao, 0.f);
}

// ---------------------------------------------------------------------------
// Phase 1: thread scans 4 adjacent columns over one chunk of pairs, with
// explicit double-buffered 4-row batch prefetch. Emits one Rec per column.
// ---------------------------------------------------------------------------
__global__ void msi_phase1(const float4* __restrict__ p4, const int4* __restrict__ s4,
                           float4* __restrict__ recs, int NC, int PCH) {
    int g = blockIdx.x * blockDim.x + threadIdx.x;   // column group (4 cols)
    int c = blockIdx.y;                              // chunk
    int t0 = c * PCH;
    int t1 = t0 + PCH; if (t1 > PAIRS) t1 = PAIRS;

    float4 pp = p4[(size_t)t0 * C4 + g];
    int4   sp = s4[(size_t)t0 * C4 + g];
    float pprev[4] = {pp.x, pp.y, pp.z, pp.w};
    int   sprev[4] = {sp.x, sp.y, sp.z, sp.w};

    float cs[4] = {0.f, 0.f, 0.f, 0.f};
    int   cc[4] = {0, 0, 0, 0};
    float hs[4] = {0.f, 0.f, 0.f, 0.f};
    int   hc[4] = {0, 0, 0, 0};
    int   hd[4] = {0, 0, 0, 0};
    float ms[4] = {0.f, 0.f, 0.f, 0.f};
    int   mc[4] = {0, 0, 0, 0};

#define PROC(PV, SV)                                                          \
    {                                                                         \
        float pcur[4] = {(PV).x, (PV).y, (PV).z, (PV).w};                     \
        int   scur[4] = {(SV).x, (SV).y, (SV).z, (SV).w};                     \
        _Pragma("unroll")                                                     \
        for (int k = 0; k < 4; ++k) {                                         \
            float d = pcur[k] - pprev[k];                                     \
            bool same = (scur[k] == sprev[k]);                                \
            bool first = !same && !hd[k];                                     \
            bool interior = !same && hd[k] && (cc[k] > 0);                    \
            hs[k] = first ? cs[k] : hs[k];                                    \
            hc[k] = first ? cc[k] : hc[k];                                    \
            float mean = cs[k] * __builtin_amdgcn_rcpf((float)cc[k]);         \
            ms[k] += interior ? mean : 0.f;                                   \
            mc[k] += interior ? 1 : 0;                                        \
            hd[k] = hd[k] | (same ? 0 : 1);                                   \
            cs[k] = same ? cs[k] + d * d : 0.f;                               \
            cc[k] = same ? cc[k] + 1 : 0;                                     \
            pprev[k] = pcur[k];                                               \
            sprev[k] = scur[k];                                               \
        }                                                                     \
    }

    int n = t1 - t0;
    int nb = n >> 2;
    size_t base = (size_t)(t0 + 1) * C4 + g;
    const size_t stride = 4 * (size_t)C4;

    if (nb > 0) {
        // prefetch first batch
        float4 P0 = p4[base], P1 = p4[base + C4], P2 = p4[base + 2 * C4], P3 = p4[base + 3 * C4];
        int4   S0 = s4[base], S1 = s4[base + C4], S2 = s4[base + 2 * C4], S3 = s4[base + 3 * C4];
        base += stride;
        #pragma unroll 2
        for (int b = 0; b < nb - 1; ++b) {
            float4 Q0 = p4[base], Q1 = p4[base + C4], Q2 = p4[base + 2 * C4], Q3 = p4[base + 3 * C4];
            int4   T0 = s4[base], T1 = s4[base + C4], T2 = s4[base + 2 * C4], T3 = s4[base + 3 * C4];
            base += stride;
            PROC(P0, S0); PROC(P1, S1); PROC(P2, S2); PROC(P3, S3);
            P0 = Q0; P1 = Q1; P2 = Q2; P3 = Q3;
            S0 = T0; S1 = T1; S2 = T2; S3 = T3;
        }
        PROC(P0, S0); PROC(P1, S1); PROC(P2, S2); PROC(P3, S3);
    }
    for (int t = t0 + (nb << 2); t < t1; ++t) {
        size_t bb = (size_t)(t + 1) * C4 + g;
        float4 P0 = p4[bb];
        int4   S0 = s4[bb];
        PROC(P0, S0);
    }
#undef PROC

    #pragma unroll
    for (int k = 0; k < 4; ++k) {
        int r = 4 * g + k;
        Rec rec;
        if (!hd[k]) {
            rec.hs = cs[k]; rec.hc = (float)cc[k];
            rec.ts = cs[k]; rec.tc = (float)cc[k];
            rec.ms = 0.f; rec.mc = 0.f; rec.ao = 1.f;
        } else {
            rec.hs = hs[k]; rec.hc = (float)hc[k];
            rec.ts = cs[k]; rec.tc = (float)cc[k];
            rec.ms = ms[k]; rec.mc = (float)mc[k]; rec.ao = 0.f;
        }
        rec_store(recs, (size_t)c * COLS + r, rec);
    }
}

// ---------------------------------------------------------------------------
// Phase 2a: merge G consecutive chunk-records per column into a super-record.
// grid = (COLS/256, NSUP); coalesced across columns.
// ---------------------------------------------------------------------------
__global__ void msi_phase2a(const float4* __restrict__ recs, float4* __restrict__ supers,
                            int G) {
    int r = blockIdx.x * blockDim.x + threadIdx.x;   // column
    int sup = blockIdx.y;
    size_t base = (size_t)sup * G * COLS + r;
    Rec acc = rec_load(recs, base);
    #pragma unroll 4
    for (int j = 1; j < G; ++j) {
        Rec nxt = rec_load(recs, base + (size_t)j * COLS);
        acc = rec_merge(acc, nxt);
    }
    rec_store(supers, (size_t)sup * COLS + r, acc);
}

// ---------------------------------------------------------------------------
// Phase 2b: merge NSUP super-records per column, finalize column contribution,
// block-reduce in double.
// ---------------------------------------------------------------------------
__global__ void msi_phase2b(const float4* __restrict__ supers, double* __restrict__ partials,
                            int NSUP) {
    int r = blockIdx.x * blockDim.x + threadIdx.x;
    Rec acc = rec_load(supers, r);
    for (int j = 1; j < NSUP; ++j)
        acc = rec_merge(acc, rec_load(supers, (size_t)j * COLS + r));

    double msum, mcnt;
    if (acc.ao != 0.f) {
        bool v = acc.hc > 0.f;
        msum = v ? (double)(acc.hs / acc.hc) : 0.0;
        mcnt = v ? 1.0 : 0.0;
    } else {
        msum = (double)acc.ms; mcnt = (double)acc.mc;
        if (acc.hc > 0.f) { msum += (double)(acc.hs / acc.hc); mcnt += 1.0; }
        if (acc.tc > 0.f) { msum += (double)(acc.ts / acc.tc); mcnt += 1.0; }
    }

    __shared__ double ls[256];
    __shared__ double lc[256];
    int tid = threadIdx.x;
    ls[tid] = msum; lc[tid] = mcnt;
    __syncthreads();
    for (int off = 128; off > 0; off >>= 1) {
        if (tid < off) { ls[tid] += ls[tid + off]; lc[tid] += lc[tid + off]; }
        __syncthreads();
    }
    if (tid == 0) {
        partials[blockIdx.x * 2 + 0] = ls[0];
        partials[blockIdx.x * 2 + 1] = lc[0];
    }
}

__global__ void msi_phase3(const double* __restrict__ partials, int nparts,
                           float* __restrict__ out) {
    int tid = threadIdx.x;
    double msum = 0.0, mcnt = 0.0;
    if (tid < nparts) {
        msum = partials[tid * 2 + 0];
        mcnt = partials[tid * 2 + 1];
    }
    for (int off = 32; off > 0; off >>= 1) {
        msum += __shfl_down(msum, off);
        mcnt += __shfl_down(mcnt, off);
    }
    if (tid == 0) out[0] = (mcnt > 0.0) ? (float)(msum / mcnt) : 0.f;
}

extern "C" void kernel_launch(void* const* d_in, const int* in_sizes, int n_in,
                              void* d_out, int out_size, void* d_ws, size_t ws_size,
                              hipStream_t stream) {
    const float4* p = (const float4*)d_in[0];
    const int4*   s = (const int4*)d_in[1];
    float* out = (float*)d_out;

    const int nblocks2 = COLS / 256;  // 16
    int NC = 128;
    auto need = [&](int nc) -> size_t {
        int gg = nc < 16 ? nc : 16;
        int nsup = nc / gg;
        return (size_t)(nc + nsup) * COLS * 32 + (size_t)nblocks2 * 2 * sizeof(double);
    };
    while (NC > 1 && need(NC) > ws_size) NC >>= 1;
    int G = NC < 16 ? NC : 16;
    int NSUP = NC / G;
    int PCH = (PAIRS + NC - 1) / NC;

    float4* recs     = (float4*)d_ws;
    float4* supers   = recs + (size_t)NC * COLS * 2;
    double* partials = (double*)(supers + (size_t)NSUP * COLS * 2);

    dim3 g1(C4 / 256, NC);        // 4 x NC blocks of 256
    msi_phase1<<<g1, 256, 0, stream>>>(p, s, recs, NC, PCH);
    dim3 g2a(COLS / 256, NSUP);
    msi_phase2a<<<g2a, 256, 0, stream>>>(recs, supers, G);
    msi_phase2b<<<nblocks2, 256, 0, stream>>>(supers, partials, NSUP);
    msi_phase3<<<1, 64, 0, stream>>>(partials, nblocks2, out);
}